// Round 7
// baseline (2381.667 us; speedup 1.0000x reference)
//
#include <hip/hip_runtime.h>

typedef float   f32x4 __attribute__((ext_vector_type(4)));
typedef _Float16 f16x8 __attribute__((ext_vector_type(8)));
typedef short   s16x8 __attribute__((ext_vector_type(8)));
typedef short   s16x4 __attribute__((ext_vector_type(4)));
typedef unsigned short u16;

#define NTOK 8192
#define CDIM 2048
#define NEXP 8
#define NASS 16384   // NTOK * TOP_K
#define MT2  10      // 256-row m-tiles per expert: covers Me <= 2560 (~+12 sigma)

#define GLOBAL_AS __attribute__((address_space(1)))
#define LDS_AS    __attribute__((address_space(3)))

__device__ __forceinline__ u16 f2h_bits(float f) {
  _Float16 h = (_Float16)f;
  union { _Float16 h; u16 u; } v;
  v.h = h;
  return v.u;
}
__device__ __forceinline__ float h2f_bits(u16 u) {
  union { u16 u; _Float16 h; } v;
  v.u = u;
  return (float)v.h;
}

// ---------- router: fp32 logits, top-2, softmax, counts, x -> f16 ----------
__global__ __launch_bounds__(256) void moe_router(
    const float* __restrict__ x, const float* __restrict__ wr,
    u16* __restrict__ xh, int* __restrict__ top_idx,
    float* __restrict__ top_p, int* __restrict__ counts)
{
  const int wave = threadIdx.x >> 6, lane = threadIdx.x & 63;
  const int n = blockIdx.x * 4 + wave;            // one wave per token
  const float* xr = x + (size_t)n * CDIM;
  u16* xhr = xh + (size_t)n * CDIM;
  float acc[NEXP] = {};
  #pragma unroll
  for (int i = 0; i < CDIM / 256; ++i) {
    const int c = i * 256 + lane * 4;
    const f32x4 xv = *(const f32x4*)(xr + c);
    s16x4 hv;
    #pragma unroll
    for (int j = 0; j < 4; ++j) hv[j] = (short)f2h_bits(xv[j]);
    *(s16x4*)(xhr + c) = hv;                      // fused x -> f16 (8B store)
    #pragma unroll
    for (int j = 0; j < 4; ++j) {
      const f32x4 w0 = *(const f32x4*)(wr + (size_t)(c + j) * NEXP);
      const f32x4 w1 = *(const f32x4*)(wr + (size_t)(c + j) * NEXP + 4);
      #pragma unroll
      for (int e = 0; e < 4; ++e) { acc[e] += xv[j] * w0[e]; acc[4 + e] += xv[j] * w1[e]; }
    }
  }
  #pragma unroll
  for (int off = 32; off > 0; off >>= 1) {
    #pragma unroll
    for (int e = 0; e < NEXP; ++e) acc[e] += __shfl_xor(acc[e], off);
  }
  if (lane == 0) {
    int i0 = 0; float v0 = acc[0];
    #pragma unroll
    for (int e = 1; e < NEXP; ++e) { if (acc[e] > v0) { v0 = acc[e]; i0 = e; } }
    int i1 = -1; float v1 = -3.4e38f;
    #pragma unroll
    for (int e = 0; e < NEXP; ++e) { if (e != i0 && acc[e] > v1) { v1 = acc[e]; i1 = e; } }
    const float ex = __expf(v1 - v0);             // softmax over the 2 kept logits
    const float p0 = 1.f / (1.f + ex);
    top_idx[n * 2 + 0] = i0; top_idx[n * 2 + 1] = i1;
    top_p[n * 2 + 0] = p0;   top_p[n * 2 + 1] = 1.f - p0;
    atomicAdd(&counts[i0], 1);
    atomicAdd(&counts[i1], 1);
  }
}

// ---------- exclusive scan of 8 counts ----------
__global__ void moe_offsets(const int* __restrict__ counts,
                            int* __restrict__ offs, int* __restrict__ fill)
{
  if (threadIdx.x == 0) {
    int s = 0;
    for (int e = 0; e < NEXP; ++e) { offs[e] = s; fill[e] = s; s += counts[e]; }
    offs[NEXP] = s;
  }
}

// ---------- scatter (token, prob) into buckets; record slot per (n,k) ----------
__global__ __launch_bounds__(256) void moe_scatter(
    const int* __restrict__ top_idx, const float* __restrict__ top_p,
    int* fill, int* __restrict__ tok_s, float* __restrict__ prb_s,
    int* __restrict__ slot_of)
{
  const int n = blockIdx.x * 256 + threadIdx.x;
  #pragma unroll
  for (int k = 0; k < 2; ++k) {
    const int e = top_idx[n * 2 + k];
    const int pos = atomicAdd(&fill[e], 1);
    tok_s[pos] = n;
    prb_s[pos] = top_p[n * 2 + k];
    slot_of[n * 2 + k] = pos;
  }
}

// ---------- transpose+convert: w [E][K][N] fp32 -> wT [E][N][K] f16 ----------
__global__ __launch_bounds__(256) void moe_transpose(
    const float* __restrict__ wfc, const float* __restrict__ wpj,
    u16* __restrict__ wfcT, u16* __restrict__ wpjT)
{
  const float* src = blockIdx.z ? wpj : wfc;
  u16* dst = blockIdx.z ? wpjT : wfcT;
  const int e = blockIdx.y;
  src += (size_t)e * CDIM * CDIM;
  dst += (size_t)e * CDIM * CDIM;
  const int tr = (blockIdx.x >> 5) * 64;   // src row (K) base
  const int tc = (blockIdx.x & 31) * 64;   // src col (N) base
  __shared__ float lds[64][65];            // +1 pad breaks bank conflicts
  const int t = threadIdx.x;
  #pragma unroll
  for (int p = 0; p < 4; ++p) {
    const int r  = p * 16 + (t >> 4);
    const int c4 = (t & 15) * 4;
    const f32x4 v = *(const f32x4*)(src + (size_t)(tr + r) * CDIM + tc + c4);
    #pragma unroll
    for (int j = 0; j < 4; ++j) lds[r][c4 + j] = v[j];
  }
  __syncthreads();
  const int d  = t >> 2;
  const int cs = (t & 3) * 16;
  s16x8 o0, o1;
  #pragma unroll
  for (int j = 0; j < 8; ++j) o0[j] = (short)f2h_bits(lds[cs + j][d]);
  #pragma unroll
  for (int j = 0; j < 8; ++j) o1[j] = (short)f2h_bits(lds[cs + 8 + j][d]);
  u16* drow = dst + (size_t)(tc + d) * CDIM + tr + cs;
  *(s16x8*)(drow + 0) = o0;
  *(s16x8*)(drow + 8) = o1;
}

// ---------- grouped GEMM: 256x256, BK=32, wave-tile 128x64, 2 blocks/CU ----------
// LDS-amplification cut: 8 waves (2Mx4N) each own 128x64 out (acc[8][4]):
// 12 ds_read_b128 serve 32 MFMA (0.375 KB/MFMA vs 0.5 at 64x64 tiles).
// dbuf 64 KB -> 2 blocks/CU fill each other's vmcnt/barrier stalls (m114).
// Counted vmcnt(4) never drains (R4 cadence, 4 loads/thread/tile).
// LDS line-paired layout (measured 0 conflicts in R4/R6):
//   phys(r,c) = line (r>>1), slot (r&1)*4 + (c ^ ((r>>1)&3))
// Expert-per-XCD dispatch (id&7=e) kept: FETCH 303->110 MB measured.
// MODE 0: H[s,:] = f16(relu(Xg @ WfcT^T)^2)    (A gathered via tok_s)
// MODE 1: Y[s,:] = f16(prb[s] * (H @ WpjT^T))  (A linear; no atomics)
template<int MODE>
__global__ __launch_bounds__(512, 4) void moe_gemm7(
    const u16* __restrict__ A, const u16* __restrict__ W,
    const int* __restrict__ tok_s, const float* __restrict__ prb_s,
    const int* __restrict__ offs, u16* __restrict__ hout)
{
  const int id    = blockIdx.x;
  const int e     = id & 7;                   // expert -> XCD co-location
  const int rid   = id >> 3;
  const int nt    = rid & 7;
  const int mtile = rid >> 3;                 // 0..MT2-1
  const int off0  = offs[e];
  const int Me    = offs[e + 1] - off0;
  const int m0    = mtile * 256;
  if (m0 >= Me) return;
  const int n0 = nt * 256;
  const u16* We = W + (size_t)e * CDIM * CDIM;

  __shared__ u16 As[2][256 * 32];   // 16 KB x2
  __shared__ u16 Bs[2][256 * 32];   // 16 KB x2  -> 64 KB total

  const int t    = threadIdx.x;
  const int lane = t & 63, wv = t >> 6;       // 8 waves
  const int wm = wv >> 2, wn = wv & 3;        // wave-tile: rows wm*128, cols wn*64

  // ---- staging precompute (line-paired layout, R4-verified) ----
  const int l     = lane;
  const int kchnk = (l & 3) ^ ((l >> 3) & 3); // source k-chunk for linear LDS fill
  const int kelem = kchnk * 8;
  const int rloc  = 2 * (l >> 3) + ((l >> 2) & 1);   // row within 16-row instr block
  const int rA0 = wv * 32 + rloc;             // A/B rows this lane stages
  const int rA1 = wv * 32 + 16 + rloc;
  int mr0 = m0 + rA0; mr0 = mr0 < Me ? mr0 : Me - 1;   // clamp tail (dup, benign)
  int mr1 = m0 + rA1; mr1 = mr1 < Me ? mr1 : Me - 1;
  const int ga0 = (MODE == 0) ? tok_s[off0 + mr0] : (off0 + mr0);
  const int ga1 = (MODE == 0) ? tok_s[off0 + mr1] : (off0 + mr1);
  const u16* asrc0 = A  + (size_t)ga0 * CDIM + kelem;
  const u16* asrc1 = A  + (size_t)ga1 * CDIM + kelem;
  const u16* bsrc0 = We + (size_t)(n0 + rA0) * CDIM + kelem;
  const u16* bsrc1 = We + (size_t)(n0 + rA1) * CDIM + kelem;

  #define STAGE(T_)                                                            \
    { const int bb_ = (T_) & 1; const int kk_ = (T_) * 32;                     \
      __builtin_amdgcn_global_load_lds(                                        \
          (const GLOBAL_AS void*)(asrc0 + kk_),                                \
          (LDS_AS void*)&As[bb_][wv * 1024], 16, 0, 0);                        \
      __builtin_amdgcn_global_load_lds(                                        \
          (const GLOBAL_AS void*)(asrc1 + kk_),                                \
          (LDS_AS void*)&As[bb_][wv * 1024 + 512], 16, 0, 0);                  \
      __builtin_amdgcn_global_load_lds(                                        \
          (const GLOBAL_AS void*)(bsrc0 + kk_),                                \
          (LDS_AS void*)&Bs[bb_][wv * 1024], 16, 0, 0);                        \
      __builtin_amdgcn_global_load_lds(                                        \
          (const GLOBAL_AS void*)(bsrc1 + kk_),                                \
          (LDS_AS void*)&Bs[bb_][wv * 1024 + 512], 16, 0, 0); }

  // ---- read addressing (per lane) ----
  const int rsel     = lane & 15;
  const int g        = lane >> 4;
  const int halfline = rsel >> 1;
  const int slotx    = (((rsel & 1) * 4) + (g ^ (halfline & 3))) * 8;  // u16 units

  f32x4 acc[8][4] = {};

  #define COMPUTE(bb)                                                          \
    { f16x8 bv[4];                                                             \
      _Pragma("unroll")                                                        \
      for (int fn = 0; fn < 4; ++fn)                                           \
        bv[fn] = *(const f16x8*)&Bs[bb][(wn * 32 + fn * 8 + halfline) * 64 + slotx]; \
      _Pragma("unroll")                                                        \
      for (int fi = 0; fi < 8; ++fi) {                                         \
        const f16x8 av = *(const f16x8*)&As[bb][(wm * 64 + fi * 8 + halfline) * 64 + slotx]; \
        _Pragma("unroll")                                                      \
        for (int fn = 0; fn < 4; ++fn)                                         \
          acc[fi][fn] = __builtin_amdgcn_mfma_f32_16x16x32_f16(                \
              av, bv[fn], acc[fi][fn], 0, 0, 0);                               \
      } }

  // Ledger (4 loads/thread/tile): STAGE(T+1) -> 8 outstanding; vmcnt(4)
  // retires exactly tile T's 4, keeps T+1 in flight -> never drains.
  STAGE(0);
  #pragma unroll 2
  for (int T = 0; T < 64; ++T) {
    if (T < 63) { STAGE(T + 1); asm volatile("s_waitcnt vmcnt(4)" ::: "memory"); }
    else        {               asm volatile("s_waitcnt vmcnt(0)" ::: "memory"); }
    __builtin_amdgcn_s_barrier();               // tile T landed for all waves
    COMPUTE(T & 1);
    __builtin_amdgcn_s_barrier();               // reads done before next overwrite
  }
  #undef STAGE
  #undef COMPUTE

  // Epilogue. C/D map: col = lane&15, row = (lane>>4)*4 + j.
  const int crow = g * 4;
  const int ccol = rsel;
  #pragma unroll
  for (int fi = 0; fi < 8; ++fi) {
    #pragma unroll
    for (int j = 0; j < 4; ++j) {
      const int r = m0 + wm * 128 + fi * 16 + crow + j;
      if (r >= Me) continue;
      const int s = off0 + r;
      u16* hr = hout + (size_t)s * CDIM;
      const float p = (MODE == 1) ? prb_s[s] : 0.f;
      #pragma unroll
      for (int fn = 0; fn < 4; ++fn) {
        float v = acc[fi][fn][j];
        if (MODE == 0) v = v > 0.f ? v * v : 0.f;     // relu^2 fused
        else           v = p * v;                     // routing weight fused
        hr[n0 + wn * 64 + fn * 16 + ccol] = f2h_bits(v);
      }
    }
  }
}

// ---------- combine: out[n,:] = y[slot0,:] + y[slot1,:] (no atomics) ----------
__global__ __launch_bounds__(256) void moe_combine(
    const u16* __restrict__ y, const int* __restrict__ slot_of,
    float* __restrict__ out)
{
  const int n = blockIdx.x;
  const int c = threadIdx.x * 8;
  const int s0 = slot_of[n * 2 + 0];
  const int s1 = slot_of[n * 2 + 1];
  const s16x8 a = *(const s16x8*)(y + (size_t)s0 * CDIM + c);
  const s16x8 b = *(const s16x8*)(y + (size_t)s1 * CDIM + c);
  f32x4 o0, o1;
  #pragma unroll
  for (int j = 0; j < 4; ++j) {
    o0[j] = h2f_bits((u16)a[j])     + h2f_bits((u16)b[j]);
    o1[j] = h2f_bits((u16)a[4 + j]) + h2f_bits((u16)b[4 + j]);
  }
  float* orow = out + (size_t)n * CDIM + c;
  *(f32x4*)(orow + 0) = o0;
  *(f32x4*)(orow + 4) = o1;
}

extern "C" void kernel_launch(void* const* d_in, const int* in_sizes, int n_in,
                              void* d_out, int out_size, void* d_ws, size_t ws_size,
                              hipStream_t stream)
{
  const float* x   = (const float*)d_in[0];
  const float* wr  = (const float*)d_in[1];
  const float* wfc = (const float*)d_in[2];
  const float* wpj = (const float*)d_in[3];
  float* out = (float*)d_out;
  char* ws = (char*)d_ws;

  const size_t OFF_TIDX = 256;
  const size_t OFF_TP   = OFF_TIDX + (size_t)NASS * 4;
  const size_t OFF_TOK  = OFF_TP   + (size_t)NASS * 4;
  const size_t OFF_PRB  = OFF_TOK  + (size_t)NASS * 4;
  const size_t OFF_SLOT = OFF_PRB  + (size_t)NASS * 4;
  const size_t OFF_XH   = (size_t)1 << 20;
  const size_t OFF_WFCT = OFF_XH   + (size_t)NTOK * CDIM * 2;
  const size_t OFF_WPJT = OFF_WFCT + (size_t)NEXP * CDIM * CDIM * 2;
  const size_t OFF_H    = OFF_WPJT + (size_t)NEXP * CDIM * CDIM * 2;
  const size_t NEED     = OFF_H    + (size_t)NASS * CDIM * 2;   // ~236 MB

  if (ws_size < NEED) {            // signal: absmax == |ref|max means ws too small
    hipMemsetAsync(d_out, 0, (size_t)out_size * 4, stream);
    return;
  }

  int*   counts = (int*)(ws + 0);
  int*   offs   = (int*)(ws + 64);
  int*   fill   = (int*)(ws + 128);
  int*   tidx   = (int*)(ws + OFF_TIDX);
  float* tp     = (float*)(ws + OFF_TP);
  int*   tok    = (int*)(ws + OFF_TOK);
  float* prb    = (float*)(ws + OFF_PRB);
  int*   slot   = (int*)(ws + OFF_SLOT);
  u16*   xh     = (u16*)(ws + OFF_XH);
  u16*   wfcT   = (u16*)(ws + OFF_WFCT);
  u16*   wpjT   = (u16*)(ws + OFF_WPJT);
  u16*   h      = (u16*)(ws + OFF_H);
  // y overlays xh+wfcT (both dead after GEMM-0): 64 MB needed, 96 MB available.
  u16*   y      = (u16*)(ws + OFF_XH);

  hipMemsetAsync(ws, 0, 256, stream);                       // counts/fill

  moe_router  <<<NTOK / 4, 256, 0, stream>>>(x, wr, xh, tidx, tp, counts);
  moe_offsets <<<1, 64, 0, stream>>>(counts, offs, fill);
  moe_scatter <<<NTOK / 256, 256, 0, stream>>>(tidx, tp, fill, tok, prb, slot);
  moe_transpose<<<dim3(1024, NEXP, 2), 256, 0, stream>>>(wfc, wpj, wfcT, wpjT);
  moe_gemm7<0><<<NEXP * 8 * MT2, 512, 0, stream>>>(xh, wfcT, tok, nullptr, offs, h);
  moe_gemm7<1><<<NEXP * 8 * MT2, 512, 0, stream>>>(h,  wpjT, tok, prb,     offs, y);
  moe_combine <<<NTOK, 256, 0, stream>>>(y, slot, out);
}

// Round 8
// 757.446 us; speedup vs baseline: 3.1443x; 3.1443x over previous
//
#include <hip/hip_runtime.h>

typedef float   f32x4 __attribute__((ext_vector_type(4)));
typedef _Float16 f16x8 __attribute__((ext_vector_type(8)));
typedef short   s16x8 __attribute__((ext_vector_type(8)));
typedef short   s16x4 __attribute__((ext_vector_type(4)));
typedef unsigned short u16;

#define NTOK 8192
#define CDIM 2048
#define NEXP 8
#define NASS 16384   // NTOK * TOP_K
#define MTILES 24    // BM=128 slack: supports Me up to 3072

#define GLOBAL_AS __attribute__((address_space(1)))
#define LDS_AS    __attribute__((address_space(3)))

__device__ __forceinline__ u16 f2h_bits(float f) {
  _Float16 h = (_Float16)f;
  union { _Float16 h; u16 u; } v;
  v.h = h;
  return v.u;
}

// ---------- tiny: wr [C][E] f32 -> wrT [E][C] f32 (coalesced router reads) ----------
__global__ __launch_bounds__(256) void moe_wrt(
    const float* __restrict__ wr, float* __restrict__ wrT)
{
  const int gid = blockIdx.x * 256 + threadIdx.x;   // 16384 elems
  const int c = gid >> 3, e = gid & 7;
  wrT[e * CDIM + c] = wr[c * NEXP + e];
}

// ---------- router: fp32 logits, top-2, softmax, counts, x -> f16 ----------
__global__ __launch_bounds__(256) void moe_router(
    const float* __restrict__ x, const float* __restrict__ wrT,
    u16* __restrict__ xh, int* __restrict__ top_idx,
    float* __restrict__ top_p, int* __restrict__ counts)
{
  const int wave = threadIdx.x >> 6, lane = threadIdx.x & 63;
  const int n = blockIdx.x * 4 + wave;            // one wave per token
  const float* xr = x + (size_t)n * CDIM;
  u16* xhr = xh + (size_t)n * CDIM;
  float acc[NEXP] = {};
  #pragma unroll
  for (int i = 0; i < CDIM / 256; ++i) {
    const int c = i * 256 + lane * 4;
    const f32x4 xv = *(const f32x4*)(xr + c);
    s16x4 hv;
    #pragma unroll
    for (int j = 0; j < 4; ++j) hv[j] = (short)f2h_bits(xv[j]);
    *(s16x4*)(xhr + c) = hv;                      // fused x -> f16 (8B store)
    #pragma unroll
    for (int e = 0; e < NEXP; ++e) {              // coalesced f32x4 per expert row
      const f32x4 wv = *(const f32x4*)(wrT + (size_t)e * CDIM + c);
      acc[e] += xv[0]*wv[0] + xv[1]*wv[1] + xv[2]*wv[2] + xv[3]*wv[3];
    }
  }
  #pragma unroll
  for (int off = 32; off > 0; off >>= 1) {
    #pragma unroll
    for (int e = 0; e < NEXP; ++e) acc[e] += __shfl_xor(acc[e], off);
  }
  if (lane == 0) {
    int i0 = 0; float v0 = acc[0];
    #pragma unroll
    for (int e = 1; e < NEXP; ++e) { if (acc[e] > v0) { v0 = acc[e]; i0 = e; } }
    int i1 = -1; float v1 = -3.4e38f;
    #pragma unroll
    for (int e = 0; e < NEXP; ++e) { if (e != i0 && acc[e] > v1) { v1 = acc[e]; i1 = e; } }
    const float ex = __expf(v1 - v0);             // softmax over the 2 kept logits
    const float p0 = 1.f / (1.f + ex);
    top_idx[n * 2 + 0] = i0; top_idx[n * 2 + 1] = i1;
    top_p[n * 2 + 0] = p0;   top_p[n * 2 + 1] = 1.f - p0;
    atomicAdd(&counts[i0], 1);
    atomicAdd(&counts[i1], 1);
  }
}

// ---------- exclusive scan of 8 counts ----------
__global__ void moe_offsets(const int* __restrict__ counts,
                            int* __restrict__ offs, int* __restrict__ fill)
{
  if (threadIdx.x == 0) {
    int s = 0;
    for (int e = 0; e < NEXP; ++e) { offs[e] = s; fill[e] = s; s += counts[e]; }
    offs[NEXP] = s;
  }
}

// ---------- scatter (token, prob) into expert buckets ----------
__global__ __launch_bounds__(256) void moe_scatter(
    const int* __restrict__ top_idx, const float* __restrict__ top_p,
    int* fill, int* __restrict__ tok_s, float* __restrict__ prb_s)
{
  const int n = blockIdx.x * 256 + threadIdx.x;
  #pragma unroll
  for (int k = 0; k < 2; ++k) {
    const int e = top_idx[n * 2 + k];
    const int pos = atomicAdd(&fill[e], 1);
    tok_s[pos] = n;
    prb_s[pos] = top_p[n * 2 + k];
  }
}

// ---------- transpose+convert: w [E][K][N] fp32 -> wT [E][N][K] f16 ----------
__global__ __launch_bounds__(256) void moe_transpose(
    const float* __restrict__ wfc, const float* __restrict__ wpj,
    u16* __restrict__ wfcT, u16* __restrict__ wpjT)
{
  const float* src = blockIdx.z ? wpj : wfc;
  u16* dst = blockIdx.z ? wpjT : wfcT;
  const int e = blockIdx.y;
  src += (size_t)e * CDIM * CDIM;
  dst += (size_t)e * CDIM * CDIM;
  const int tr = (blockIdx.x >> 5) * 64;   // src row (K) base
  const int tc = (blockIdx.x & 31) * 64;   // src col (N) base
  __shared__ float lds[64][65];            // +1 pad breaks bank conflicts
  const int t = threadIdx.x;
  #pragma unroll
  for (int p = 0; p < 4; ++p) {
    const int r  = p * 16 + (t >> 4);
    const int c4 = (t & 15) * 4;
    const f32x4 v = *(const f32x4*)(src + (size_t)(tr + r) * CDIM + tc + c4);
    #pragma unroll
    for (int j = 0; j < 4; ++j) lds[r][c4 + j] = v[j];
  }
  __syncthreads();
  const int d  = t >> 2;
  const int cs = (t & 3) * 16;
  s16x8 o0, o1;
  #pragma unroll
  for (int j = 0; j < 8; ++j) o0[j] = (short)f2h_bits(lds[cs + j][d]);
  #pragma unroll
  for (int j = 0; j < 8; ++j) o1[j] = (short)f2h_bits(lds[cs + 8 + j][d]);
  u16* drow = dst + (size_t)(tc + d) * CDIM + tr + cs;
  *(s16x8*)(drow + 0) = o0;
  *(s16x8*)(drow + 8) = o1;
}

// ---------- grouped GEMM: 128x256, BK=32, 3-buffer depth-2 prefetch ----------
// n-tile-per-XCD dispatch (id&7 = nt -> XCD): PERFECT load balance (every
// n-tile sums the same work over all experts, unlike expert-pinning where
// XCD time ∝ Me skew). rid is e-major so same-expert blocks co-dispatch ->
// B-slice stays XCD-L2-hot per expert phase.
// 8 waves (2Mx4N), wave-tile 64x64, acc[4][4]; LDS 72 KB -> 2 blocks/CU.
// Ledger (3 loads/wave/tile): prologue {0,1,2}=9; iter T: vmcnt(6) retires
// tile T (leaves {T+1,T+2}); barrier; COMPUTE(bufT); barrier; STAGE(T+3 -> bufT).
// LDS line-paired layout (measured 0 conflicts R4/R6):
//   phys(r,c) = line (r>>1), slot (r&1)*4 + (c ^ ((r>>1)&3))
// MODE 0: H[s,:] = f16(relu(Xg @ WfcT^T)^2)   (A = xh gathered via tok_s)
// MODE 1: out[tok,:] += prb * (H @ WpjT^T)    (A = h linear; atomic combine)
template<int MODE>
__global__ __launch_bounds__(512, 4) void moe_gemm8(
    const u16* __restrict__ A, const u16* __restrict__ W,
    const int* __restrict__ tok_s, const float* __restrict__ prb_s,
    const int* __restrict__ offs, u16* __restrict__ hout,
    float* __restrict__ out)
{
  const int id    = blockIdx.x;
  const int nt    = id & 7;                   // n-tile -> XCD (balance + B locality)
  const int rid   = id >> 3;                  // e-major: rid = e*MTILES + mtile
  const int e     = rid / MTILES;
  const int mtile = rid % MTILES;
  const int off0  = offs[e];
  const int Me    = offs[e + 1] - off0;
  const int m0    = mtile * 128;
  if (m0 >= Me) return;
  const int n0 = nt * 256;
  const u16* We = W + (size_t)e * CDIM * CDIM;

  __shared__ u16 As[3][128 * 32];   // 8 KB x3
  __shared__ u16 Bs[3][256 * 32];   // 16 KB x3  -> 72 KB total

  const int t    = threadIdx.x;
  const int lane = t & 63, wv = t >> 6;       // 8 waves
  const int wm = wv >> 2, wn = wv & 3;        // wave-tile: rows wm*64, cols wn*64

  // ---- staging precompute (per lane) ----
  const int l     = lane;
  const int kchnk = (l & 3) ^ ((l >> 3) & 3); // source k-chunk for linear LDS fill
  const int kelem = kchnk * 8;
  const int rloc  = 2 * (l >> 3) + ((l >> 2) & 1);   // row within 16-row instr block
  const int rA  = wv * 16 + rloc;
  const int mrA = m0 + rA;
  const int rrA = (mrA < Me) ? mrA : (Me - 1);       // clamp tail (dup, benign)
  const int gaA = (MODE == 0) ? tok_s[off0 + rrA] : (off0 + rrA);
  const u16* asrc = A + (size_t)gaA * CDIM + kelem;
  const int rB0 = wv * 32 + rloc;
  const int rB1 = wv * 32 + 16 + rloc;
  const u16* bsrc0 = We + (size_t)(n0 + rB0) * CDIM + kelem;
  const u16* bsrc1 = We + (size_t)(n0 + rB1) * CDIM + kelem;

  #define STAGE(T_, bb_)                                                       \
    { const int kk_ = (T_) * 32;                                               \
      __builtin_amdgcn_global_load_lds(                                        \
          (const GLOBAL_AS void*)(asrc + kk_),                                 \
          (LDS_AS void*)&As[bb_][wv * 512], 16, 0, 0);                         \
      __builtin_amdgcn_global_load_lds(                                        \
          (const GLOBAL_AS void*)(bsrc0 + kk_),                                \
          (LDS_AS void*)&Bs[bb_][wv * 1024], 16, 0, 0);                        \
      __builtin_amdgcn_global_load_lds(                                        \
          (const GLOBAL_AS void*)(bsrc1 + kk_),                                \
          (LDS_AS void*)&Bs[bb_][wv * 1024 + 512], 16, 0, 0); }

  // ---- read addressing (per lane) ----
  const int rsel     = lane & 15;
  const int g        = lane >> 4;
  const int halfline = rsel >> 1;
  const int slotx    = (((rsel & 1) * 4) + (g ^ (halfline & 3))) * 8;  // u16 units

  f32x4 acc[4][4] = {};

  #define COMPUTE(bb)                                                          \
    { f16x8 bv[4];                                                             \
      _Pragma("unroll")                                                        \
      for (int fn = 0; fn < 4; ++fn)                                           \
        bv[fn] = *(const f16x8*)&Bs[bb][(wn * 32 + fn * 8 + halfline) * 64 + slotx]; \
      _Pragma("unroll")                                                        \
      for (int fi = 0; fi < 4; ++fi) {                                         \
        const f16x8 av = *(const f16x8*)&As[bb][(wm * 32 + fi * 8 + halfline) * 64 + slotx]; \
        _Pragma("unroll")                                                      \
        for (int fn = 0; fn < 4; ++fn)                                         \
          acc[fi][fn] = __builtin_amdgcn_mfma_f32_16x16x32_f16(                \
              av, bv[fn], acc[fi][fn], 0, 0, 0);                               \
      } }

  STAGE(0, 0); STAGE(1, 1); STAGE(2, 2);        // 9 in flight
  int bb = 0;
  #pragma unroll 3
  for (int T = 0; T < 64; ++T) {
    if (T < 62)       { asm volatile("s_waitcnt vmcnt(6)" ::: "memory"); }
    else if (T == 62) { asm volatile("s_waitcnt vmcnt(3)" ::: "memory"); }
    else              { asm volatile("s_waitcnt vmcnt(0)" ::: "memory"); }
    __builtin_amdgcn_s_barrier();               // all waves' tile-T loads landed
    COMPUTE(bb);
    __builtin_amdgcn_s_barrier();               // reads done before re-staging buf
    if (T < 61) STAGE(T + 3, bb);               // (T+3)%3 == T%3 == bb
    bb = (bb == 2) ? 0 : bb + 1;
  }
  #undef STAGE
  #undef COMPUTE

  // Epilogue. C/D map: col = lane&15, row = (lane>>4)*4 + j.
  const int crow = g * 4;
  const int ccol = rsel;
  #pragma unroll
  for (int fi = 0; fi < 4; ++fi) {
    #pragma unroll
    for (int j = 0; j < 4; ++j) {
      const int r = m0 + wm * 64 + fi * 16 + crow + j;
      if (r >= Me) continue;
      const int s = off0 + r;
      if (MODE == 0) {
        u16* hr = hout + (size_t)s * CDIM;
        #pragma unroll
        for (int fn = 0; fn < 4; ++fn) {
          float v = acc[fi][fn][j];
          v = v > 0.f ? v * v : 0.f;                  // relu^2 fused
          hr[n0 + wn * 64 + fn * 16 + ccol] = f2h_bits(v);
        }
      } else {
        const float p = prb_s[s];
        float* orow = out + (size_t)tok_s[s] * CDIM;
        #pragma unroll
        for (int fn = 0; fn < 4; ++fn)
          atomicAdd(&orow[n0 + wn * 64 + fn * 16 + ccol], p * acc[fi][fn][j]);
      }
    }
  }
}

extern "C" void kernel_launch(void* const* d_in, const int* in_sizes, int n_in,
                              void* d_out, int out_size, void* d_ws, size_t ws_size,
                              hipStream_t stream)
{
  const float* x   = (const float*)d_in[0];
  const float* wr  = (const float*)d_in[1];
  const float* wfc = (const float*)d_in[2];
  const float* wpj = (const float*)d_in[3];
  float* out = (float*)d_out;
  char* ws = (char*)d_ws;

  const size_t OFF_TIDX = 256;
  const size_t OFF_TP   = OFF_TIDX + (size_t)NASS * 4;
  const size_t OFF_TOK  = OFF_TP   + (size_t)NASS * 4;
  const size_t OFF_PRB  = OFF_TOK  + (size_t)NASS * 4;
  const size_t OFF_WRT  = OFF_PRB  + (size_t)NASS * 4;          // 64 KB f32
  const size_t OFF_XH   = (size_t)1 << 20;
  const size_t OFF_WFCT = OFF_XH   + (size_t)NTOK * CDIM * 2;
  const size_t OFF_WPJT = OFF_WFCT + (size_t)NEXP * CDIM * CDIM * 2;
  const size_t OFF_H    = OFF_WPJT + (size_t)NEXP * CDIM * CDIM * 2;
  const size_t NEED     = OFF_H    + (size_t)NASS * CDIM * 2;   // ~236 MB

  if (ws_size < NEED) {            // signal: absmax == |ref|max means ws too small
    hipMemsetAsync(d_out, 0, (size_t)out_size * 4, stream);
    return;
  }

  int*   counts = (int*)(ws + 0);
  int*   offs   = (int*)(ws + 64);
  int*   fill   = (int*)(ws + 128);
  int*   tidx   = (int*)(ws + OFF_TIDX);
  float* tp     = (float*)(ws + OFF_TP);
  int*   tok    = (int*)(ws + OFF_TOK);
  float* prb    = (float*)(ws + OFF_PRB);
  float* wrT    = (float*)(ws + OFF_WRT);
  u16*   xh     = (u16*)(ws + OFF_XH);
  u16*   wfcT   = (u16*)(ws + OFF_WFCT);
  u16*   wpjT   = (u16*)(ws + OFF_WPJT);
  u16*   h      = (u16*)(ws + OFF_H);

  hipMemsetAsync(ws, 0, 256, stream);                       // counts/fill
  hipMemsetAsync(d_out, 0, (size_t)out_size * 4, stream);   // atomic target

  moe_wrt     <<<NEXP * CDIM / 256, 256, 0, stream>>>(wr, wrT);
  moe_router  <<<NTOK / 4, 256, 0, stream>>>(x, wrT, xh, tidx, tp, counts);
  moe_offsets <<<1, 64, 0, stream>>>(counts, offs, fill);
  moe_scatter <<<NTOK / 256, 256, 0, stream>>>(tidx, tp, fill, tok, prb);
  moe_transpose<<<dim3(1024, NEXP, 2), 256, 0, stream>>>(wfc, wpj, wfcT, wpjT);
  moe_gemm8<0><<<NEXP * 8 * MTILES, 512, 0, stream>>>(xh, wfcT, tok, nullptr, offs, h, nullptr);
  moe_gemm8<1><<<NEXP * 8 * MTILES, 512, 0, stream>>>(h,  wpjT, tok, prb,     offs, nullptr, out);
}

// Round 9
// 610.826 us; speedup vs baseline: 3.8991x; 1.2400x over previous
//
#include <hip/hip_runtime.h>

typedef float   f32x4 __attribute__((ext_vector_type(4)));
typedef _Float16 f16x8 __attribute__((ext_vector_type(8)));
typedef short   s16x8 __attribute__((ext_vector_type(8)));
typedef short   s16x4 __attribute__((ext_vector_type(4)));
typedef unsigned short u16;

#define NTOK 8192
#define CDIM 2048
#define NEXP 8
#define NASS 16384   // NTOK * TOP_K
#define MTILES 24    // BM=128 slack: supports Me up to 3072

#define GLOBAL_AS __attribute__((address_space(1)))
#define LDS_AS    __attribute__((address_space(3)))

__device__ __forceinline__ u16 f2h_bits(float f) {
  _Float16 h = (_Float16)f;
  union { _Float16 h; u16 u; } v;
  v.h = h;
  return v.u;
}

// ---------- tiny: wr [C][E] f32 -> wrT [E][C] f32 (coalesced router reads) ----------
__global__ __launch_bounds__(256) void moe_wrt(
    const float* __restrict__ wr, float* __restrict__ wrT)
{
  const int gid = blockIdx.x * 256 + threadIdx.x;   // 16384 elems
  const int c = gid >> 3, e = gid & 7;
  wrT[e * CDIM + c] = wr[c * NEXP + e];
}

// ---------- router: grid-stride, LDS count reduce (8 atomics/block) ----------
__global__ __launch_bounds__(256) void moe_router(
    const float* __restrict__ x, const float* __restrict__ wrT,
    u16* __restrict__ xh, int* __restrict__ top_idx,
    float* __restrict__ top_p, int* __restrict__ counts)
{
  __shared__ int scnt[NEXP];
  if (threadIdx.x < NEXP) scnt[threadIdx.x] = 0;
  __syncthreads();
  const int wave = threadIdx.x >> 6, lane = threadIdx.x & 63;
  for (int i = 0; i < 8; ++i) {                   // 32 tokens per block
    const int n = blockIdx.x * 32 + i * 4 + wave;
    const float* xr = x + (size_t)n * CDIM;
    u16* xhr = xh + (size_t)n * CDIM;
    float acc[NEXP] = {};
    #pragma unroll
    for (int ii = 0; ii < CDIM / 256; ++ii) {
      const int c = ii * 256 + lane * 4;
      const f32x4 xv = *(const f32x4*)(xr + c);
      s16x4 hv;
      #pragma unroll
      for (int j = 0; j < 4; ++j) hv[j] = (short)f2h_bits(xv[j]);
      *(s16x4*)(xhr + c) = hv;                    // fused x -> f16 (8B store)
      #pragma unroll
      for (int e = 0; e < NEXP; ++e) {            // coalesced f32x4 per expert row
        const f32x4 wv = *(const f32x4*)(wrT + (size_t)e * CDIM + c);
        acc[e] += xv[0]*wv[0] + xv[1]*wv[1] + xv[2]*wv[2] + xv[3]*wv[3];
      }
    }
    #pragma unroll
    for (int off = 32; off > 0; off >>= 1) {
      #pragma unroll
      for (int e = 0; e < NEXP; ++e) acc[e] += __shfl_xor(acc[e], off);
    }
    if (lane == 0) {
      int i0 = 0; float v0 = acc[0];
      #pragma unroll
      for (int e = 1; e < NEXP; ++e) { if (acc[e] > v0) { v0 = acc[e]; i0 = e; } }
      int i1 = -1; float v1 = -3.4e38f;
      #pragma unroll
      for (int e = 0; e < NEXP; ++e) { if (e != i0 && acc[e] > v1) { v1 = acc[e]; i1 = e; } }
      const float ex = __expf(v1 - v0);           // softmax over the 2 kept logits
      const float p0 = 1.f / (1.f + ex);
      top_idx[n * 2 + 0] = i0; top_idx[n * 2 + 1] = i1;
      top_p[n * 2 + 0] = p0;   top_p[n * 2 + 1] = 1.f - p0;
      atomicAdd(&scnt[i0], 1);                    // LDS atomics (cheap)
      atomicAdd(&scnt[i1], 1);
    }
  }
  __syncthreads();
  if (threadIdx.x < NEXP) atomicAdd(&counts[threadIdx.x], scnt[threadIdx.x]);
}

// ---------- exclusive scan of 8 counts ----------
__global__ void moe_offsets(const int* __restrict__ counts,
                            int* __restrict__ offs, int* __restrict__ fill)
{
  if (threadIdx.x == 0) {
    int s = 0;
    for (int e = 0; e < NEXP; ++e) { offs[e] = s; fill[e] = s; s += counts[e]; }
    offs[NEXP] = s;
  }
}

// ---------- scatter (token, prob) into expert buckets ----------
__global__ __launch_bounds__(256) void moe_scatter(
    const int* __restrict__ top_idx, const float* __restrict__ top_p,
    int* fill, int* __restrict__ tok_s, float* __restrict__ prb_s)
{
  const int n = blockIdx.x * 256 + threadIdx.x;
  #pragma unroll
  for (int k = 0; k < 2; ++k) {
    const int e = top_idx[n * 2 + k];
    const int pos = atomicAdd(&fill[e], 1);
    tok_s[pos] = n;
    prb_s[pos] = top_p[n * 2 + k];
  }
}

// ---------- transpose+convert: w [E][K][N] fp32 -> wT [E][N][K] f16 ----------
// 64 K-rows x 128 N-cols per block (bigger tiles, half the blocks of R8).
__global__ __launch_bounds__(256) void moe_transpose(
    const float* __restrict__ wfc, const float* __restrict__ wpj,
    u16* __restrict__ wfcT, u16* __restrict__ wpjT)
{
  const float* src = blockIdx.z ? wpj : wfc;
  u16* dst = blockIdx.z ? wpjT : wfcT;
  const int e = blockIdx.y;
  src += (size_t)e * CDIM * CDIM;
  dst += (size_t)e * CDIM * CDIM;
  const int tr = (blockIdx.x >> 4) * 64;    // src row (K) base, 32 tiles
  const int tc = (blockIdx.x & 15) * 128;   // src col (N) base, 16 tiles
  __shared__ float lds[64][129];            // +1 pad breaks bank conflicts
  const int t = threadIdx.x;
  #pragma unroll
  for (int p = 0; p < 8; ++p) {
    const int r  = p * 8 + (t >> 5);
    const int c4 = (t & 31) * 4;
    const f32x4 v = *(const f32x4*)(src + (size_t)(tr + r) * CDIM + tc + c4);
    #pragma unroll
    for (int j = 0; j < 4; ++j) lds[r][c4 + j] = v[j];
  }
  __syncthreads();
  const int d  = t >> 1;                    // out row (N-local), 0..127
  const int ks = (t & 1) * 32;              // K base this thread writes
  u16* drow = dst + (size_t)(tc + d) * CDIM + tr + ks;
  #pragma unroll
  for (int q = 0; q < 4; ++q) {
    s16x8 o;
    #pragma unroll
    for (int j = 0; j < 8; ++j) o[j] = (short)f2h_bits(lds[ks + q * 8 + j][d]);
    *(s16x8*)(drow + q * 8) = o;
  }
}

// ---------- grouped GEMM: 128x256, BK=32, 3-buffer SINGLE-BARRIER pipeline ----------
// Change vs R8: stage tile T+2 (into the buffer last READ at iter T-1) right
// after the opening barrier -> the closing barrier is provably redundant:
// a wave passing iter T's barrier has consumed all its iter T-1 ds_reads
// (every read feeds an MFMA; operand waits precede issue). Halves barrier
// count and overlaps stage-issue with compute (T14).
// Ledger (3 loads/wave/tile): prologue {0,1}=6; iter T: vmcnt(3) retires
// tile T exactly (T+1 stays in flight); barrier; STAGE(T+2); COMPUTE(T%3).
// n-tile-per-XCD dispatch (id&7 = nt): perfect balance (R8: 277->242).
// LDS line-paired layout (measured 0 conflicts R4/R6/R8):
//   phys(r,c) = line (r>>1), slot (r&1)*4 + (c ^ ((r>>1)&3))
// MODE 0: H[s,:] = f16(relu(Xg @ WfcT^T)^2)   (A = xh gathered via tok_s)
// MODE 1: out[tok,:] += prb * (H @ WpjT^T)    (A = h linear; atomic combine)
template<int MODE>
__global__ __launch_bounds__(512, 4) void moe_gemm9(
    const u16* __restrict__ A, const u16* __restrict__ W,
    const int* __restrict__ tok_s, const float* __restrict__ prb_s,
    const int* __restrict__ offs, u16* __restrict__ hout,
    float* __restrict__ out)
{
  const int id    = blockIdx.x;
  const int nt    = id & 7;                   // n-tile -> XCD (balance + B locality)
  const int rid   = id >> 3;                  // e-major: rid = e*MTILES + mtile
  const int e     = rid / MTILES;
  const int mtile = rid % MTILES;
  const int off0  = offs[e];
  const int Me    = offs[e + 1] - off0;
  const int m0    = mtile * 128;
  if (m0 >= Me) return;
  const int n0 = nt * 256;
  const u16* We = W + (size_t)e * CDIM * CDIM;

  __shared__ u16 As[3][128 * 32];   // 8 KB x3
  __shared__ u16 Bs[3][256 * 32];   // 16 KB x3  -> 72 KB total

  const int t    = threadIdx.x;
  const int lane = t & 63, wv = t >> 6;       // 8 waves
  const int wm = wv >> 2, wn = wv & 3;        // wave-tile: rows wm*64, cols wn*64

  // ---- staging precompute (per lane) ----
  const int l     = lane;
  const int kchnk = (l & 3) ^ ((l >> 3) & 3); // source k-chunk for linear LDS fill
  const int kelem = kchnk * 8;
  const int rloc  = 2 * (l >> 3) + ((l >> 2) & 1);   // row within 16-row instr block
  const int rA  = wv * 16 + rloc;
  const int mrA = m0 + rA;
  const int rrA = (mrA < Me) ? mrA : (Me - 1);       // clamp tail (dup, benign)
  const int gaA = (MODE == 0) ? tok_s[off0 + rrA] : (off0 + rrA);
  const u16* asrc = A + (size_t)gaA * CDIM + kelem;
  const int rB0 = wv * 32 + rloc;
  const int rB1 = wv * 32 + 16 + rloc;
  const u16* bsrc0 = We + (size_t)(n0 + rB0) * CDIM + kelem;
  const u16* bsrc1 = We + (size_t)(n0 + rB1) * CDIM + kelem;

  #define STAGE(T_, bb_)                                                       \
    { const int kk_ = (T_) * 32;                                               \
      __builtin_amdgcn_global_load_lds(                                        \
          (const GLOBAL_AS void*)(asrc + kk_),                                 \
          (LDS_AS void*)&As[bb_][wv * 512], 16, 0, 0);                         \
      __builtin_amdgcn_global_load_lds(                                        \
          (const GLOBAL_AS void*)(bsrc0 + kk_),                                \
          (LDS_AS void*)&Bs[bb_][wv * 1024], 16, 0, 0);                        \
      __builtin_amdgcn_global_load_lds(                                        \
          (const GLOBAL_AS void*)(bsrc1 + kk_),                                \
          (LDS_AS void*)&Bs[bb_][wv * 1024 + 512], 16, 0, 0); }

  // ---- read addressing (per lane) ----
  const int rsel     = lane & 15;
  const int g        = lane >> 4;
  const int halfline = rsel >> 1;
  const int slotx    = (((rsel & 1) * 4) + (g ^ (halfline & 3))) * 8;  // u16 units

  f32x4 acc[4][4] = {};

  #define COMPUTE(bb)                                                          \
    { f16x8 bv[4];                                                             \
      _Pragma("unroll")                                                        \
      for (int fn = 0; fn < 4; ++fn)                                           \
        bv[fn] = *(const f16x8*)&Bs[bb][(wn * 32 + fn * 8 + halfline) * 64 + slotx]; \
      _Pragma("unroll")                                                        \
      for (int fi = 0; fi < 4; ++fi) {                                         \
        const f16x8 av = *(const f16x8*)&As[bb][(wm * 32 + fi * 8 + halfline) * 64 + slotx]; \
        _Pragma("unroll")                                                      \
        for (int fn = 0; fn < 4; ++fn)                                         \
          acc[fi][fn] = __builtin_amdgcn_mfma_f32_16x16x32_f16(                \
              av, bv[fn], acc[fi][fn], 0, 0, 0);                               \
      } }

  STAGE(0, 0); STAGE(1, 1);                     // 6 in flight
  int bb = 0;
  #pragma unroll 3
  for (int T = 0; T < 64; ++T) {
    if (T < 63) { asm volatile("s_waitcnt vmcnt(3)" ::: "memory"); }
    else        { asm volatile("s_waitcnt vmcnt(0)" ::: "memory"); }
    __builtin_amdgcn_s_barrier();               // tile T landed for all waves
    if (T < 62) {                               // stage T+2 into buf last read T-1
      const int b2 = (bb >= 1) ? bb - 1 : bb + 2;   // (T+2)%3
      STAGE(T + 2, b2);
    }
    COMPUTE(bb);                                // no closing barrier needed
    bb = (bb == 2) ? 0 : bb + 1;
  }
  #undef STAGE
  #undef COMPUTE

  // Epilogue. C/D map: col = lane&15, row = (lane>>4)*4 + j.
  const int crow = g * 4;
  const int ccol = rsel;
  #pragma unroll
  for (int fi = 0; fi < 4; ++fi) {
    #pragma unroll
    for (int j = 0; j < 4; ++j) {
      const int r = m0 + wm * 64 + fi * 16 + crow + j;
      if (r >= Me) continue;
      const int s = off0 + r;
      if (MODE == 0) {
        u16* hr = hout + (size_t)s * CDIM;
        #pragma unroll
        for (int fn = 0; fn < 4; ++fn) {
          float v = acc[fi][fn][j];
          v = v > 0.f ? v * v : 0.f;                  // relu^2 fused
          hr[n0 + wn * 64 + fn * 16 + ccol] = f2h_bits(v);
        }
      } else {
        const float p = prb_s[s];
        float* orow = out + (size_t)tok_s[s] * CDIM;
        #pragma unroll
        for (int fn = 0; fn < 4; ++fn)
          atomicAdd(&orow[n0 + wn * 64 + fn * 16 + ccol], p * acc[fi][fn][j]);
      }
    }
  }
}

extern "C" void kernel_launch(void* const* d_in, const int* in_sizes, int n_in,
                              void* d_out, int out_size, void* d_ws, size_t ws_size,
                              hipStream_t stream)
{
  const float* x   = (const float*)d_in[0];
  const float* wr  = (const float*)d_in[1];
  const float* wfc = (const float*)d_in[2];
  const float* wpj = (const float*)d_in[3];
  float* out = (float*)d_out;
  char* ws = (char*)d_ws;

  const size_t OFF_TIDX = 256;
  const size_t OFF_TP   = OFF_TIDX + (size_t)NASS * 4;
  const size_t OFF_TOK  = OFF_TP   + (size_t)NASS * 4;
  const size_t OFF_PRB  = OFF_TOK  + (size_t)NASS * 4;
  const size_t OFF_WRT  = OFF_PRB  + (size_t)NASS * 4;          // 64 KB f32
  const size_t OFF_XH   = (size_t)1 << 20;
  const size_t OFF_WFCT = OFF_XH   + (size_t)NTOK * CDIM * 2;
  const size_t OFF_WPJT = OFF_WFCT + (size_t)NEXP * CDIM * CDIM * 2;
  const size_t OFF_H    = OFF_WPJT + (size_t)NEXP * CDIM * CDIM * 2;
  const size_t NEED     = OFF_H    + (size_t)NASS * CDIM * 2;   // ~236 MB

  if (ws_size < NEED) {            // signal: absmax == |ref|max means ws too small
    hipMemsetAsync(d_out, 0, (size_t)out_size * 4, stream);
    return;
  }

  int*   counts = (int*)(ws + 0);
  int*   offs   = (int*)(ws + 64);
  int*   fill   = (int*)(ws + 128);
  int*   tidx   = (int*)(ws + OFF_TIDX);
  float* tp     = (float*)(ws + OFF_TP);
  int*   tok    = (int*)(ws + OFF_TOK);
  float* prb    = (float*)(ws + OFF_PRB);
  float* wrT    = (float*)(ws + OFF_WRT);
  u16*   xh     = (u16*)(ws + OFF_XH);
  u16*   wfcT   = (u16*)(ws + OFF_WFCT);
  u16*   wpjT   = (u16*)(ws + OFF_WPJT);
  u16*   h      = (u16*)(ws + OFF_H);

  hipMemsetAsync(ws, 0, 256, stream);                       // counts/fill
  hipMemsetAsync(d_out, 0, (size_t)out_size * 4, stream);   // atomic target

  moe_wrt     <<<NEXP * CDIM / 256, 256, 0, stream>>>(wr, wrT);
  moe_router  <<<256, 256, 0, stream>>>(x, wrT, xh, tidx, tp, counts);
  moe_offsets <<<1, 64, 0, stream>>>(counts, offs, fill);
  moe_scatter <<<NTOK / 256, 256, 0, stream>>>(tidx, tp, fill, tok, prb);
  moe_transpose<<<dim3(512, NEXP, 2), 256, 0, stream>>>(wfc, wpj, wfcT, wpjT);
  moe_gemm9<0><<<NEXP * 8 * MTILES, 512, 0, stream>>>(xh, wfcT, tok, nullptr, offs, h, nullptr);
  moe_gemm9<1><<<NEXP * 8 * MTILES, 512, 0, stream>>>(h,  wpjT, tok, prb,     offs, nullptr, out);
}